// Round 1
// baseline (484.790 us; speedup 1.0000x reference)
//
#include <hip/hip_runtime.h>
#include <hip/hip_bf16.h>

typedef __attribute__((ext_vector_type(8))) short short8;
typedef __attribute__((ext_vector_type(4))) float f32x4;
typedef __attribute__((ext_vector_type(4))) unsigned short u16x4;

#define S_LEN 2048
#define DH 64
#define NH 16

__device__ __forceinline__ unsigned short f2bf(float f) {
  unsigned int u = __float_as_uint(f);
  u += 0x7fffu + ((u >> 16) & 1u);   // round-to-nearest-even
  return (unsigned short)(u >> 16);
}

__global__ void convert_f2bf(const float* __restrict__ in,
                             unsigned short* __restrict__ out, int n) {
  int i = (blockIdx.x * blockDim.x + threadIdx.x) * 4;
  if (i >= n) return;
  float4 v = *reinterpret_cast<const float4*>(in + i);
  u16x4 o;
  o.x = f2bf(v.x); o.y = f2bf(v.y); o.z = f2bf(v.z); o.w = f2bf(v.w);
  *reinterpret_cast<u16x4*>(out + i) = o;
}

// C = A @ B^T   (A: [M][K] bf16 row-major, B: [N][K] bf16 row-major)
// MODE 0: out bf16 at [(b*16+h)*2048+s][64] (Q/K layout, row=(b,s), col=(h,d))
// MODE 2: out bf16 at [(b*16+h)*64+d][2048] (V transposed)
// MODE 3: out fp32 row-major [M][N]
template <int MODE>
__global__ __launch_bounds__(256) void gemm_bt(
    const unsigned short* __restrict__ A,
    const unsigned short* __restrict__ B,
    void* __restrict__ out, int M, int N, int K) {
  __shared__ __align__(16) unsigned short As[128 * 64];
  __shared__ __align__(16) unsigned short Bs[128 * 64];
  const int tid = threadIdx.x;
  const int l = tid & 63, w = tid >> 6;
  const int wr = w >> 1, wc = w & 1;
  const int g = l >> 4, c = l & 15;
  const int m0 = blockIdx.y * 128;
  const int n0 = blockIdx.x * 128;

  f32x4 acc[4][4] = {};

  const int str = tid >> 3;        // staging row within 32-row pass
  const int stc = (tid & 7) * 8;   // staging col (8 bf16 = 16B)

  for (int k0 = 0; k0 < K; k0 += 64) {
#pragma unroll
    for (int p = 0; p < 4; ++p) {
      int r = p * 32 + str;
      *reinterpret_cast<short8*>(&As[r * 64 + stc]) =
          *reinterpret_cast<const short8*>(&A[(long)(m0 + r) * K + k0 + stc]);
      *reinterpret_cast<short8*>(&Bs[r * 64 + stc]) =
          *reinterpret_cast<const short8*>(&B[(long)(n0 + r) * K + k0 + stc]);
    }
    __syncthreads();
#pragma unroll
    for (int s = 0; s < 2; ++s) {
      short8 af[4], bf[4];
#pragma unroll
      for (int m = 0; m < 4; ++m)
        af[m] = *reinterpret_cast<const short8*>(
            &As[(wr * 64 + m * 16 + c) * 64 + s * 32 + g * 8]);
#pragma unroll
      for (int n = 0; n < 4; ++n)
        bf[n] = *reinterpret_cast<const short8*>(
            &Bs[(wc * 64 + n * 16 + c) * 64 + s * 32 + g * 8]);
#pragma unroll
      for (int m = 0; m < 4; ++m)
#pragma unroll
        for (int n = 0; n < 4; ++n)
          acc[m][n] = __builtin_amdgcn_mfma_f32_16x16x32_bf16(
              af[m], bf[n], acc[m][n], 0, 0, 0);
    }
    __syncthreads();
  }

#pragma unroll
  for (int m = 0; m < 4; ++m) {
#pragma unroll
    for (int n = 0; n < 4; ++n) {
#pragma unroll
      for (int r = 0; r < 4; ++r) {
        int row = m0 + wr * 64 + m * 16 + g * 4 + r;
        int col = n0 + wc * 64 + n * 16 + c;
        float v = acc[m][n][r];
        if (MODE == 3) {
          reinterpret_cast<float*>(out)[(long)row * N + col] = v;
        } else if (MODE == 2) {
          int b = row >> 11, s = row & 2047;
          int h = col >> 6, d = col & 63;
          reinterpret_cast<unsigned short*>(
              out)[((long)((b * NH + h) * DH + d)) * S_LEN + s] = f2bf(v);
        } else {
          int b = row >> 11, s = row & 2047;
          int h = col >> 6, d = col & 63;
          reinterpret_cast<unsigned short*>(
              out)[((long)((b * NH + h) * S_LEN + s)) * DH + d] = f2bf(v);
        }
      }
    }
  }
}

// Causal flash attention. Q,K: [bh][2048][64] bf16; Vt: [bh][64][2048] bf16.
// O: [b*2048+s][1024] bf16.  Grid: (32 qblocks, 64 bh), 256 threads (4 waves).
__global__ __launch_bounds__(256) void attn_fwd(
    const unsigned short* __restrict__ Q, const unsigned short* __restrict__ Kg,
    const unsigned short* __restrict__ Vt, unsigned short* __restrict__ O) {
  __shared__ __align__(16) unsigned short Ks[32 * 64];
  __shared__ __align__(16) unsigned short Vts[64 * 32];
  __shared__ __align__(16) unsigned short Ps[4][16 * 32];

  const int tid = threadIdx.x;
  const int l = tid & 63, w = tid >> 6;
  const int g = l >> 4, c = l & 15;
  const int q0 = blockIdx.x * 64;
  const int bh = blockIdx.y;
  const int b = bh >> 4, h = bh & 15;
  const long base = (long)bh * S_LEN * DH;

  short8 aq[2];
  {
    int qrow = q0 + w * 16 + c;
    const unsigned short* qp = Q + base + (long)qrow * DH;
    aq[0] = *reinterpret_cast<const short8*>(qp + g * 8);
    aq[1] = *reinterpret_cast<const short8*>(qp + 32 + g * 8);
  }

  f32x4 o[4] = {};
  float m_r[4], l_r[4];
#pragma unroll
  for (int r = 0; r < 4; ++r) { m_r[r] = -1e30f; l_r[r] = 0.f; }

  const int nt_wave = (q0 + w * 16 + 15) / 32 + 1;
  const int nt_block = (q0 + 63) / 32 + 1;

  for (int t = 0; t < nt_block; ++t) {
    const int kv0 = t * 32;
    {
      int r = tid >> 3, cc = (tid & 7) * 8;         // K tile 32x64
      *reinterpret_cast<short8*>(&Ks[r * 64 + cc]) =
          *reinterpret_cast<const short8*>(&Kg[base + (long)(kv0 + r) * DH + cc]);
      int vr = tid >> 2, vc = (tid & 3) * 8;        // Vt tile 64x32
      *reinterpret_cast<short8*>(&Vts[vr * 32 + vc]) =
          *reinterpret_cast<const short8*>(&Vt[base + (long)vr * S_LEN + kv0 + vc]);
    }
    __syncthreads();

    if (t < nt_wave) {
      f32x4 sacc[2] = {};
#pragma unroll
      for (int n = 0; n < 2; ++n)
#pragma unroll
        for (int s = 0; s < 2; ++s) {
          short8 bk = *reinterpret_cast<const short8*>(
              &Ks[(n * 16 + c) * 64 + s * 32 + g * 8]);
          sacc[n] = __builtin_amdgcn_mfma_f32_16x16x32_bf16(aq[s], bk, sacc[n],
                                                            0, 0, 0);
        }
#pragma unroll
      for (int r = 0; r < 4; ++r) {
        int row = q0 + w * 16 + g * 4 + r;
        float s0 = sacc[0][r] * 0.125f;
        float s1 = sacc[1][r] * 0.125f;
        if (kv0 + c > row) s0 = -1e30f;
        if (kv0 + 16 + c > row) s1 = -1e30f;
        float mx = fmaxf(s0, s1);
#pragma unroll
        for (int d = 1; d < 16; d <<= 1) mx = fmaxf(mx, __shfl_xor(mx, d, 64));
        float mn = fmaxf(m_r[r], mx);
        float sc = __expf(m_r[r] - mn);
        float p0 = __expf(s0 - mn);
        float p1 = __expf(s1 - mn);
        float ps = p0 + p1;
#pragma unroll
        for (int d = 1; d < 16; d <<= 1) ps += __shfl_xor(ps, d, 64);
        l_r[r] = l_r[r] * sc + ps;
        m_r[r] = mn;
        o[0][r] *= sc; o[1][r] *= sc; o[2][r] *= sc; o[3][r] *= sc;
        Ps[w][(g * 4 + r) * 32 + c] = f2bf(p0);
        Ps[w][(g * 4 + r) * 32 + 16 + c] = f2bf(p1);
      }
      short8 pa = *reinterpret_cast<const short8*>(&Ps[w][c * 32 + g * 8]);
#pragma unroll
      for (int n = 0; n < 4; ++n) {
        short8 bv = *reinterpret_cast<const short8*>(
            &Vts[(n * 16 + c) * 32 + g * 8]);
        o[n] = __builtin_amdgcn_mfma_f32_16x16x32_bf16(pa, bv, o[n], 0, 0, 0);
      }
    }
    __syncthreads();
  }

#pragma unroll
  for (int r = 0; r < 4; ++r) {
    float inv = 1.0f / l_r[r];
    int row = q0 + w * 16 + g * 4 + r;
    long obase = ((long)(b * S_LEN + row)) * 1024 + h * DH;
#pragma unroll
    for (int n = 0; n < 4; ++n) O[obase + n * 16 + c] = f2bf(o[n][r] * inv);
  }
}

extern "C" void kernel_launch(void* const* d_in, const int* in_sizes, int n_in,
                              void* d_out, int out_size, void* d_ws,
                              size_t ws_size, hipStream_t stream) {
  const float* x  = (const float*)d_in[0];
  const float* Wq = (const float*)d_in[1];
  const float* Wk = (const float*)d_in[2];
  const float* Wv = (const float*)d_in[3];
  const float* Wo = (const float*)d_in[4];
  float* out = (float*)d_out;
  char* ws = (char*)d_ws;

  // workspace layout (40 MB):
  unsigned short* xb  = (unsigned short*)(ws);                   // 16 MB (reused as O)
  unsigned short* Wqb = (unsigned short*)(ws + (16u << 20));
  unsigned short* Wkb = (unsigned short*)(ws + (18u << 20));
  unsigned short* Wvb = (unsigned short*)(ws + (20u << 20));
  unsigned short* Wob = (unsigned short*)(ws + (22u << 20));
  unsigned short* Vt  = (unsigned short*)(ws + (24u << 20));     // 16 MB
  unsigned short* Ow  = (unsigned short*)(ws);                   // alias xb (dead after V proj)
  // Q/K bf16 scratch inside d_out (32 MB fp32) — overwritten by final GEMM
  unsigned short* Qw = (unsigned short*)d_out;
  unsigned short* Kw = (unsigned short*)d_out + (8u << 20);

  const int NX = 8 * 1024 * 1024, NW = 1024 * 1024;
  convert_f2bf<<<NX / 1024, 256, 0, stream>>>(x, xb, NX);
  convert_f2bf<<<NW / 1024, 256, 0, stream>>>(Wq, Wqb, NW);
  convert_f2bf<<<NW / 1024, 256, 0, stream>>>(Wk, Wkb, NW);
  convert_f2bf<<<NW / 1024, 256, 0, stream>>>(Wv, Wvb, NW);
  convert_f2bf<<<NW / 1024, 256, 0, stream>>>(Wo, Wob, NW);

  dim3 ggrid(8, 64);  // N/128, M/128
  gemm_bt<0><<<ggrid, 256, 0, stream>>>(xb, Wqb, Qw, 8192, 1024, 1024);
  gemm_bt<0><<<ggrid, 256, 0, stream>>>(xb, Wkb, Kw, 8192, 1024, 1024);
  gemm_bt<2><<<ggrid, 256, 0, stream>>>(xb, Wvb, Vt, 8192, 1024, 1024);

  attn_fwd<<<dim3(32, 64), 256, 0, stream>>>(Qw, Kw, Vt, Ow);

  gemm_bt<3><<<ggrid, 256, 0, stream>>>(Ow, Wob, out, 8192, 1024, 1024);
}

// Round 2
// 282.025 us; speedup vs baseline: 1.7190x; 1.7190x over previous
//
#include <hip/hip_runtime.h>
#include <hip/hip_bf16.h>

typedef __attribute__((ext_vector_type(8))) short short8;
typedef __attribute__((ext_vector_type(4))) float f32x4;
typedef __attribute__((ext_vector_type(4))) unsigned short u16x4;

#define S_LEN 2048
#define DH 64
#define NH 16

__device__ __forceinline__ unsigned short f2bf(float f) {
  unsigned int u = __float_as_uint(f);
  u += 0x7fffu + ((u >> 16) & 1u);   // round-to-nearest-even
  return (unsigned short)(u >> 16);
}

__global__ void convert_f2bf(const float* __restrict__ in,
                             unsigned short* __restrict__ out, int n) {
  int i = (blockIdx.x * blockDim.x + threadIdx.x) * 4;
  if (i >= n) return;
  float4 v = *reinterpret_cast<const float4*>(in + i);
  u16x4 o;
  o.x = f2bf(v.x); o.y = f2bf(v.y); o.z = f2bf(v.z); o.w = f2bf(v.w);
  *reinterpret_cast<u16x4*>(out + i) = o;
}

// C = A @ B^T   (A: [M][K] bf16 row-major, B: [N][K] bf16 row-major)
// MODE 0: out bf16 at [(b*16+h)*2048+s][64] (Q/K layout, row=(b,s), col=(h,d))
// MODE 2: out bf16 at [(b*16+h)*64+d][2048] (V transposed)
// MODE 3: out fp32 row-major [M][N]
template <int MODE>
__global__ __launch_bounds__(256) void gemm_bt(
    const unsigned short* __restrict__ A,
    const unsigned short* __restrict__ B,
    void* __restrict__ out, int M, int N, int K) {
  __shared__ __align__(16) unsigned short As[128 * 64];
  __shared__ __align__(16) unsigned short Bs[128 * 64];
  const int tid = threadIdx.x;
  const int l = tid & 63, w = tid >> 6;
  const int wr = w >> 1, wc = w & 1;
  const int g = l >> 4, c = l & 15;
  const int m0 = blockIdx.y * 128;
  const int n0 = blockIdx.x * 128;

  f32x4 acc[4][4] = {};

  const int str = tid >> 3;        // staging row within 32-row pass
  const int stc = (tid & 7) * 8;   // staging col (8 bf16 = 16B)

  for (int k0 = 0; k0 < K; k0 += 64) {
#pragma unroll
    for (int p = 0; p < 4; ++p) {
      int r = p * 32 + str;
      *reinterpret_cast<short8*>(&As[r * 64 + stc]) =
          *reinterpret_cast<const short8*>(&A[(long)(m0 + r) * K + k0 + stc]);
      *reinterpret_cast<short8*>(&Bs[r * 64 + stc]) =
          *reinterpret_cast<const short8*>(&B[(long)(n0 + r) * K + k0 + stc]);
    }
    __syncthreads();
#pragma unroll
    for (int s = 0; s < 2; ++s) {
      short8 af[4], bf[4];
#pragma unroll
      for (int m = 0; m < 4; ++m)
        af[m] = *reinterpret_cast<const short8*>(
            &As[(wr * 64 + m * 16 + c) * 64 + s * 32 + g * 8]);
#pragma unroll
      for (int n = 0; n < 4; ++n)
        bf[n] = *reinterpret_cast<const short8*>(
            &Bs[(wc * 64 + n * 16 + c) * 64 + s * 32 + g * 8]);
#pragma unroll
      for (int m = 0; m < 4; ++m)
#pragma unroll
        for (int n = 0; n < 4; ++n)
          acc[m][n] = __builtin_amdgcn_mfma_f32_16x16x32_bf16(
              af[m], bf[n], acc[m][n], 0, 0, 0);
    }
    __syncthreads();
  }

#pragma unroll
  for (int m = 0; m < 4; ++m) {
#pragma unroll
    for (int n = 0; n < 4; ++n) {
#pragma unroll
      for (int r = 0; r < 4; ++r) {
        int row = m0 + wr * 64 + m * 16 + g * 4 + r;
        int col = n0 + wc * 64 + n * 16 + c;
        float v = acc[m][n][r];
        if (MODE == 3) {
          reinterpret_cast<float*>(out)[(long)row * N + col] = v;
        } else if (MODE == 2) {
          int b = row >> 11, s = row & 2047;
          int h = col >> 6, d = col & 63;
          reinterpret_cast<unsigned short*>(
              out)[((long)((b * NH + h) * DH + d)) * S_LEN + s] = f2bf(v);
        } else {
          int b = row >> 11, s = row & 2047;
          int h = col >> 6, d = col & 63;
          reinterpret_cast<unsigned short*>(
              out)[((long)((b * NH + h) * S_LEN + s)) * DH + d] = f2bf(v);
        }
      }
    }
  }
}

// ---- attention v2: KVBLK=64, XOR-swizzled LDS, longest-blocks-first ----
// swizzled element offset within a row-major [R][64] bf16 tile
__device__ __forceinline__ int swz8c(int row, int chunk) {   // 8-elem chunk idx
  return row * 64 + ((chunk ^ (row & 7)) << 3);
}
__device__ __forceinline__ int swze(int row, int col) {      // scalar element
  return row * 64 + ((((col >> 3) ^ (row & 7)) << 3) | (col & 7));
}

// Q,K: [bh][2048][64] bf16; Vt: [bh][64][2048] bf16; O: [b*2048+s][1024] bf16.
// Grid: (64 bh, 32 qblocks reversed), 256 threads (4 waves x 16 q-rows).
__global__ __launch_bounds__(256) void attn_fwd(
    const unsigned short* __restrict__ Q, const unsigned short* __restrict__ Kg,
    const unsigned short* __restrict__ Vt, unsigned short* __restrict__ O) {
  __shared__ __align__(16) unsigned short Ks[64 * 64];
  __shared__ __align__(16) unsigned short Vts[64 * 64];
  __shared__ __align__(16) unsigned short Ps[4][16 * 64];

  const int tid = threadIdx.x;
  const int l = tid & 63, w = tid >> 6;
  const int g = l >> 4, c = l & 15;
  const int bh = blockIdx.x;
  const int qb = 31 - blockIdx.y;          // longest blocks dispatched first
  const int q0 = qb * 64;
  const int b = bh >> 4, h = bh & 15;
  const long base = (long)bh * S_LEN * DH;

  short8 aq[2];
  {
    int qrow = q0 + w * 16 + c;
    const unsigned short* qp = Q + base + (long)qrow * DH;
    aq[0] = *reinterpret_cast<const short8*>(qp + g * 8);
    aq[1] = *reinterpret_cast<const short8*>(qp + 32 + g * 8);
  }

  f32x4 o[4] = {};
  float m_r[4], l_r[4];
#pragma unroll
  for (int r = 0; r < 4; ++r) { m_r[r] = -1e30f; l_r[r] = 0.f; }

  const int nt = qb + 1;
  const int sr = tid >> 3;            // staging row 0..31
  const int sck = tid & 7;            // staging chunk

  for (int t = 0; t < nt; ++t) {
    const int kv0 = t * 64;
#pragma unroll
    for (int p = 0; p < 2; ++p) {
      int rr = sr + p * 32;
      *reinterpret_cast<short8*>(&Ks[swz8c(rr, sck)]) =
          *reinterpret_cast<const short8*>(
              &Kg[base + (long)(kv0 + rr) * DH + sck * 8]);
      *reinterpret_cast<short8*>(&Vts[swz8c(rr, sck)]) =
          *reinterpret_cast<const short8*>(
              &Vt[base + (long)rr * S_LEN + kv0 + sck * 8]);
    }
    __syncthreads();

    // QK^T: 16 q-rows x 64 kv
    f32x4 sacc[4] = {};
#pragma unroll
    for (int n = 0; n < 4; ++n)
#pragma unroll
      for (int s = 0; s < 2; ++s) {
        short8 bk = *reinterpret_cast<const short8*>(
            &Ks[swz8c(n * 16 + c, s * 4 + g)]);
        sacc[n] = __builtin_amdgcn_mfma_f32_16x16x32_bf16(aq[s], bk, sacc[n],
                                                          0, 0, 0);
      }

    const bool last = (t == nt - 1);
#pragma unroll
    for (int r = 0; r < 4; ++r) {
      int row = q0 + w * 16 + g * 4 + r;
      float s0 = sacc[0][r] * 0.125f;
      float s1 = sacc[1][r] * 0.125f;
      float s2 = sacc[2][r] * 0.125f;
      float s3 = sacc[3][r] * 0.125f;
      if (last) {
        if (kv0 + c > row) s0 = -1e30f;
        if (kv0 + 16 + c > row) s1 = -1e30f;
        if (kv0 + 32 + c > row) s2 = -1e30f;
        if (kv0 + 48 + c > row) s3 = -1e30f;
      }
      float mx = fmaxf(fmaxf(s0, s1), fmaxf(s2, s3));
#pragma unroll
      for (int d = 1; d < 16; d <<= 1) mx = fmaxf(mx, __shfl_xor(mx, d, 64));
      float mn = fmaxf(m_r[r], mx);
      float sc = __expf(m_r[r] - mn);
      float p0 = __expf(s0 - mn);
      float p1 = __expf(s1 - mn);
      float p2 = __expf(s2 - mn);
      float p3 = __expf(s3 - mn);
      float ps = (p0 + p1) + (p2 + p3);
#pragma unroll
      for (int d = 1; d < 16; d <<= 1) ps += __shfl_xor(ps, d, 64);
      l_r[r] = l_r[r] * sc + ps;
      m_r[r] = mn;
      o[0][r] *= sc; o[1][r] *= sc; o[2][r] *= sc; o[3][r] *= sc;
      int prow = g * 4 + r;
      Ps[w][swze(prow, c)] = f2bf(p0);
      Ps[w][swze(prow, 16 + c)] = f2bf(p1);
      Ps[w][swze(prow, 32 + c)] = f2bf(p2);
      Ps[w][swze(prow, 48 + c)] = f2bf(p3);
    }

    // PV: o[n] += P(16x64) * V^T rows (d = n*16+c), k = kv
#pragma unroll
    for (int s = 0; s < 2; ++s) {
      short8 pa = *reinterpret_cast<const short8*>(&Ps[w][swz8c(c, s * 4 + g)]);
#pragma unroll
      for (int n = 0; n < 4; ++n) {
        short8 bv = *reinterpret_cast<const short8*>(
            &Vts[swz8c(n * 16 + c, s * 4 + g)]);
        o[n] = __builtin_amdgcn_mfma_f32_16x16x32_bf16(pa, bv, o[n], 0, 0, 0);
      }
    }
    __syncthreads();
  }

#pragma unroll
  for (int r = 0; r < 4; ++r) {
    float inv = 1.0f / l_r[r];
    int row = q0 + w * 16 + g * 4 + r;
    long obase = ((long)(b * S_LEN + row)) * 1024 + h * DH;
#pragma unroll
    for (int n = 0; n < 4; ++n) O[obase + n * 16 + c] = f2bf(o[n][r] * inv);
  }
}

extern "C" void kernel_launch(void* const* d_in, const int* in_sizes, int n_in,
                              void* d_out, int out_size, void* d_ws,
                              size_t ws_size, hipStream_t stream) {
  const float* x  = (const float*)d_in[0];
  const float* Wq = (const float*)d_in[1];
  const float* Wk = (const float*)d_in[2];
  const float* Wv = (const float*)d_in[3];
  const float* Wo = (const float*)d_in[4];
  float* out = (float*)d_out;
  char* ws = (char*)d_ws;

  // workspace layout (40 MB):
  unsigned short* xb  = (unsigned short*)(ws);                   // 16 MB (reused as O)
  unsigned short* Wqb = (unsigned short*)(ws + (16u << 20));
  unsigned short* Wkb = (unsigned short*)(ws + (18u << 20));
  unsigned short* Wvb = (unsigned short*)(ws + (20u << 20));
  unsigned short* Wob = (unsigned short*)(ws + (22u << 20));
  unsigned short* Vt  = (unsigned short*)(ws + (24u << 20));     // 16 MB
  unsigned short* Ow  = (unsigned short*)(ws);                   // alias xb (dead after V proj)
  // Q/K bf16 scratch inside d_out (32 MB fp32) — overwritten by final GEMM
  unsigned short* Qw = (unsigned short*)d_out;
  unsigned short* Kw = (unsigned short*)d_out + (8u << 20);

  const int NX = 8 * 1024 * 1024, NW = 1024 * 1024;
  convert_f2bf<<<NX / 1024, 256, 0, stream>>>(x, xb, NX);
  convert_f2bf<<<NW / 1024, 256, 0, stream>>>(Wq, Wqb, NW);
  convert_f2bf<<<NW / 1024, 256, 0, stream>>>(Wk, Wkb, NW);
  convert_f2bf<<<NW / 1024, 256, 0, stream>>>(Wv, Wvb, NW);
  convert_f2bf<<<NW / 1024, 256, 0, stream>>>(Wo, Wob, NW);

  dim3 ggrid(8, 64);  // N/128, M/128
  gemm_bt<0><<<ggrid, 256, 0, stream>>>(xb, Wqb, Qw, 8192, 1024, 1024);
  gemm_bt<0><<<ggrid, 256, 0, stream>>>(xb, Wkb, Kw, 8192, 1024, 1024);
  gemm_bt<2><<<ggrid, 256, 0, stream>>>(xb, Wvb, Vt, 8192, 1024, 1024);

  attn_fwd<<<dim3(64, 32), 256, 0, stream>>>(Qw, Kw, Vt, Ow);

  gemm_bt<3><<<ggrid, 256, 0, stream>>>(Ow, Wob, out, 8192, 1024, 1024);
}

// Round 4
// 251.741 us; speedup vs baseline: 1.9257x; 1.1203x over previous
//
#include <hip/hip_runtime.h>
#include <hip/hip_bf16.h>

typedef __attribute__((ext_vector_type(8))) short short8;
typedef __attribute__((ext_vector_type(4))) float f32x4;
typedef __attribute__((ext_vector_type(16))) float f32x16;
typedef __attribute__((ext_vector_type(4))) unsigned short u16x4;

#define S_LEN 2048
#define DH 64
#define NH 16
#define SCALE_LOG2 0.18033688011112042f  // (1/8) * log2(e)

#define EXP2F(x) __builtin_amdgcn_exp2f(x)

__device__ __forceinline__ unsigned short f2bf(float f) {
  unsigned int u = __float_as_uint(f);
  u += 0x7fffu + ((u >> 16) & 1u);   // round-to-nearest-even
  return (unsigned short)(u >> 16);
}

__device__ __forceinline__ unsigned int cvtpk(float a, float b) {
  unsigned int r;
  asm("v_cvt_pk_bf16_f32 %0, %1, %2" : "=v"(r) : "v"(a), "v"(b));
  return r;
}
__device__ __forceinline__ void plswap(unsigned int& a, unsigned int& b) {
  asm("v_permlane32_swap_b32 %0, %1" : "+v"(a), "+v"(b));
}

__global__ void convert_f2bf(const float* __restrict__ in,
                             unsigned short* __restrict__ out, int n) {
  int i = (blockIdx.x * blockDim.x + threadIdx.x) * 4;
  if (i >= n) return;
  float4 v = *reinterpret_cast<const float4*>(in + i);
  u16x4 o;
  o.x = f2bf(v.x); o.y = f2bf(v.y); o.z = f2bf(v.z); o.w = f2bf(v.w);
  *reinterpret_cast<u16x4*>(out + i) = o;
}

// C = A @ B^T   (A: [M][K] bf16 row-major, B: [N][K] bf16 row-major)
// MODE 0: out bf16 at [(b*16+h)*2048+s][64]  (K layout)
// MODE 1: like 0 but scaled by SCALE_LOG2    (Q layout)
// MODE 2: out bf16 at [(b*16+h)*64+d][2048]  (V transposed)
// MODE 3: out fp32 row-major [M][N]
template <int MODE>
__global__ __launch_bounds__(256) void gemm_bt(
    const unsigned short* __restrict__ A,
    const unsigned short* __restrict__ B,
    void* __restrict__ out, int M, int N, int K) {
  __shared__ __align__(16) unsigned short As[128 * 64];
  __shared__ __align__(16) unsigned short Bs[128 * 64];
  const int tid = threadIdx.x;
  const int l = tid & 63, w = tid >> 6;
  const int wr = w >> 1, wc = w & 1;
  const int g = l >> 4, c = l & 15;
  const int m0 = blockIdx.y * 128;
  const int n0 = blockIdx.x * 128;
  const int lrow = l >> 3, lcol = (l & 7) * 8;  // lane slot in 8-row pass

  f32x4 acc[4][4] = {};

  for (int k0 = 0; k0 < K; k0 += 64) {
#pragma unroll
    for (int p = 0; p < 4; ++p) {
      int r0 = w * 32 + p * 8;
      __builtin_amdgcn_global_load_lds(
          (const __attribute__((address_space(1))) void*)
              &A[(long)(m0 + r0 + lrow) * K + k0 + lcol],
          (__attribute__((address_space(3))) void*)&As[r0 * 64], 16, 0, 0);
      __builtin_amdgcn_global_load_lds(
          (const __attribute__((address_space(1))) void*)
              &B[(long)(n0 + r0 + lrow) * K + k0 + lcol],
          (__attribute__((address_space(3))) void*)&Bs[r0 * 64], 16, 0, 0);
    }
    __syncthreads();
#pragma unroll
    for (int s = 0; s < 2; ++s) {
      short8 af[4], bf[4];
#pragma unroll
      for (int m = 0; m < 4; ++m)
        af[m] = *reinterpret_cast<const short8*>(
            &As[(wr * 64 + m * 16 + c) * 64 + s * 32 + g * 8]);
#pragma unroll
      for (int n = 0; n < 4; ++n)
        bf[n] = *reinterpret_cast<const short8*>(
            &Bs[(wc * 64 + n * 16 + c) * 64 + s * 32 + g * 8]);
#pragma unroll
      for (int m = 0; m < 4; ++m)
#pragma unroll
        for (int n = 0; n < 4; ++n)
          acc[m][n] = __builtin_amdgcn_mfma_f32_16x16x32_bf16(
              af[m], bf[n], acc[m][n], 0, 0, 0);
    }
    __syncthreads();
  }

#pragma unroll
  for (int m = 0; m < 4; ++m) {
#pragma unroll
    for (int n = 0; n < 4; ++n) {
#pragma unroll
      for (int r = 0; r < 4; ++r) {
        int row = m0 + wr * 64 + m * 16 + g * 4 + r;
        int col = n0 + wc * 64 + n * 16 + c;
        float v = acc[m][n][r];
        if (MODE == 3) {
          reinterpret_cast<float*>(out)[(long)row * N + col] = v;
        } else if (MODE == 2) {
          int b = row >> 11, s = row & 2047;
          int h = col >> 6, d = col & 63;
          reinterpret_cast<unsigned short*>(
              out)[((long)((b * NH + h) * DH + d)) * S_LEN + s] = f2bf(v);
        } else {
          if (MODE == 1) v *= SCALE_LOG2;
          int b = row >> 11, s = row & 2047;
          int h = col >> 6, d = col & 63;
          reinterpret_cast<unsigned short*>(
              out)[((long)((b * NH + h) * S_LEN + s)) * DH + d] = f2bf(v);
        }
      }
    }
  }
}

// swizzled 8-elem-chunk offset within a row-major [R][64] bf16 tile
__device__ __forceinline__ int swz8c(int row, int chunk) {
  return row * 64 + ((chunk ^ (row & 7)) << 3);
}

// ---- attention v3: swapped 32x32 QK^T, in-register softmax (T12/T13) ----
// Q (pre-scaled by SCALE_LOG2), K: [bh][2048][64] bf16; Vt: [bh][64][2048];
// O: [b*2048+s][1024] bf16. Grid: (16 qb interleaved, 64 bh), 256 thr (4 waves).
__global__ __launch_bounds__(256) void attn_fwd(
    const unsigned short* __restrict__ Q, const unsigned short* __restrict__ Kg,
    const unsigned short* __restrict__ Vt, unsigned short* __restrict__ O) {
  __shared__ __align__(16) unsigned short Ks[64 * 64];
  __shared__ __align__(16) unsigned short Vs[64 * 64];

  const int tid = threadIdx.x;
  const int l = tid & 63;
  const int w = tid >> 6;
  const int ln = l & 31;
  const int hi = l >> 5;
  const int hi4 = hi * 4;
  const int xx = blockIdx.x;
  const int qb = (xx & 1) ? (15 - (xx >> 1)) : (xx >> 1);  // pair long+short
  const int q0 = qb * 128;
  const int bh = blockIdx.y;
  const int b = bh >> 4, h = bh & 15;
  const long base = (long)bh * (S_LEN * DH);
  const int q0w = q0 + w * 32;

  // Q B-fragments: lane holds Q[q0w+ln][ks*16 + hi*8 + j]
  short8 qf[4];
  {
    const unsigned short* qp = Q + base + (long)(q0w + ln) * DH + hi * 8;
#pragma unroll
    for (int ks = 0; ks < 4; ++ks)
      qf[ks] = *reinterpret_cast<const short8*>(qp + ks * 16);
  }

  f32x16 o0 = {}, o1 = {};
  float m_r = -1e30f, l_r = 0.f;

  const int ntw = q0w / 64 + 1;      // tiles this wave computes
  const int ntb = qb * 2 + 2;        // tiles this block stages

  const int srow = tid >> 2;          // staging row 0..63
  const int sce = (tid & 3) * 16;     // element col (2 chunks of 8)
  const int sc0 = sce >> 3;

  for (int t = 0; t < ntb; ++t) {
    const int kv0 = t * 64;
    __syncthreads();
    {
      const unsigned short* ksrc = Kg + base + (long)(kv0 + srow) * DH + sce;
      const unsigned short* vsrc = Vt + base + (long)srow * S_LEN + kv0 + sce;
      *reinterpret_cast<short8*>(&Ks[swz8c(srow, sc0)]) =
          *reinterpret_cast<const short8*>(ksrc);
      *reinterpret_cast<short8*>(&Ks[swz8c(srow, sc0 + 1)]) =
          *reinterpret_cast<const short8*>(ksrc + 8);
      *reinterpret_cast<short8*>(&Vs[swz8c(srow, sc0)]) =
          *reinterpret_cast<const short8*>(vsrc);
      *reinterpret_cast<short8*>(&Vs[swz8c(srow, sc0 + 1)]) =
          *reinterpret_cast<const short8*>(vsrc + 8);
    }
    __syncthreads();
    if (t >= ntw) continue;

    // swapped QK^T: S^T[kv][q], kv in regs, q = lane column
    f32x16 s0 = {}, s1 = {};
#pragma unroll
    for (int ks = 0; ks < 4; ++ks) {
      short8 ak0 = *reinterpret_cast<const short8*>(&Ks[swz8c(ln, ks * 2 + hi)]);
      short8 ak1 =
          *reinterpret_cast<const short8*>(&Ks[swz8c(32 + ln, ks * 2 + hi)]);
      s0 = __builtin_amdgcn_mfma_f32_32x32x16_bf16(ak0, qf[ks], s0, 0, 0, 0);
      s1 = __builtin_amdgcn_mfma_f32_32x32x16_bf16(ak1, qf[ks], s1, 0, 0, 0);
    }

    if (t == ntw - 1) {  // diagonal tile: causal mask (kv > q)
      const int qrel = (q0w - kv0) + ln;
#pragma unroll
      for (int r = 0; r < 16; ++r) {
        const int rowv = (r & 3) + 8 * (r >> 2) + hi4;
        if (rowv > qrel) s0[r] = -1e30f;
        if (rowv + 32 > qrel) s1[r] = -1e30f;
      }
    }

    float pm = -1e30f;
#pragma unroll
    for (int r = 0; r < 16; ++r) pm = fmaxf(pm, fmaxf(s0[r], s1[r]));
    pm = fmaxf(pm, __shfl_xor(pm, 32, 64));

    if (!__all(pm <= m_r + 8.0f)) {  // T13 defer-max
      float mn = fmaxf(m_r, pm);
      float sc = EXP2F(m_r - mn);
      m_r = mn;
      l_r *= sc;
#pragma unroll
      for (int r = 0; r < 16; ++r) {
        float sv = __shfl(sc, (r & 3) + 8 * (r >> 2) + hi4, 64);
        o0[r] *= sv;
        o1[r] *= sv;
      }
    }

    float ps = 0.f;
#pragma unroll
    for (int r = 0; r < 16; ++r) {
      s0[r] = EXP2F(s0[r] - m_r);
      s1[r] = EXP2F(s1[r] - m_r);
      ps += s0[r] + s1[r];
    }
    ps += __shfl_xor(ps, 32, 64);
    l_r += ps;

    // PV: rebuild P A-fragment in-register (T12) and accumulate O
#pragma unroll
    for (int ks = 0; ks < 4; ++ks) {
      unsigned int wa, wb, wc2, wd;
      if (ks == 0) {
        wa = cvtpk(s0[0], s0[1]);  wc2 = cvtpk(s0[2], s0[3]);
        wb = cvtpk(s0[4], s0[5]);  wd  = cvtpk(s0[6], s0[7]);
      } else if (ks == 1) {
        wa = cvtpk(s0[8], s0[9]);  wc2 = cvtpk(s0[10], s0[11]);
        wb = cvtpk(s0[12], s0[13]); wd = cvtpk(s0[14], s0[15]);
      } else if (ks == 2) {
        wa = cvtpk(s1[0], s1[1]);  wc2 = cvtpk(s1[2], s1[3]);
        wb = cvtpk(s1[4], s1[5]);  wd  = cvtpk(s1[6], s1[7]);
      } else {
        wa = cvtpk(s1[8], s1[9]);  wc2 = cvtpk(s1[10], s1[11]);
        wb = cvtpk(s1[12], s1[13]); wd = cvtpk(s1[14], s1[15]);
      }
      plswap(wa, wb);   // -> word0, word2
      plswap(wc2, wd);  // -> word1, word3
      union { unsigned int u[4]; short8 s; } pa;
      pa.u[0] = wa; pa.u[1] = wc2; pa.u[2] = wb; pa.u[3] = wd;
      short8 v0 = *reinterpret_cast<const short8*>(&Vs[swz8c(ln, ks * 2 + hi)]);
      short8 v1 =
          *reinterpret_cast<const short8*>(&Vs[swz8c(32 + ln, ks * 2 + hi)]);
      o0 = __builtin_amdgcn_mfma_f32_32x32x16_bf16(pa.s, v0, o0, 0, 0, 0);
      o1 = __builtin_amdgcn_mfma_f32_32x32x16_bf16(pa.s, v1, o1, 0, 0, 0);
    }
  }

  float inv = 1.0f / l_r;
#pragma unroll
  for (int r = 0; r < 16; ++r) {
    const int rowv = (r & 3) + 8 * (r >> 2) + hi4;
    float iv = __shfl(inv, rowv, 64);
    int q = q0w + rowv;
    long ob = ((long)(b * S_LEN + q)) * 1024 + h * 64 + ln;
    O[ob] = f2bf(o0[r] * iv);
    O[ob + 32] = f2bf(o1[r] * iv);
  }
}

extern "C" void kernel_launch(void* const* d_in, const int* in_sizes, int n_in,
                              void* d_out, int out_size, void* d_ws,
                              size_t ws_size, hipStream_t stream) {
  const float* x  = (const float*)d_in[0];
  const float* Wq = (const float*)d_in[1];
  const float* Wk = (const float*)d_in[2];
  const float* Wv = (const float*)d_in[3];
  const float* Wo = (const float*)d_in[4];
  float* out = (float*)d_out;
  char* ws = (char*)d_ws;

  unsigned short* xb  = (unsigned short*)(ws);                   // 16 MB
  unsigned short* Wqb = (unsigned short*)(ws + (16u << 20));
  unsigned short* Wkb = (unsigned short*)(ws + (18u << 20));
  unsigned short* Wvb = (unsigned short*)(ws + (20u << 20));
  unsigned short* Wob = (unsigned short*)(ws + (22u << 20));
  unsigned short* Vt  = (unsigned short*)(ws + (24u << 20));     // 16 MB
  unsigned short* Ow  = (unsigned short*)(ws);                   // alias xb
  unsigned short* Qw = (unsigned short*)d_out;                   // scratch in d_out
  unsigned short* Kw = (unsigned short*)d_out + (8u << 20);

  const int NX = 8 * 1024 * 1024, NW = 1024 * 1024;
  convert_f2bf<<<NX / 1024, 256, 0, stream>>>(x, xb, NX);
  convert_f2bf<<<NW / 1024, 256, 0, stream>>>(Wq, Wqb, NW);
  convert_f2bf<<<NW / 1024, 256, 0, stream>>>(Wk, Wkb, NW);
  convert_f2bf<<<NW / 1024, 256, 0, stream>>>(Wv, Wvb, NW);
  convert_f2bf<<<NW / 1024, 256, 0, stream>>>(Wo, Wob, NW);

  dim3 ggrid(8, 64);  // N/128, M/128
  gemm_bt<1><<<ggrid, 256, 0, stream>>>(xb, Wqb, Qw, 8192, 1024, 1024);
  gemm_bt<0><<<ggrid, 256, 0, stream>>>(xb, Wkb, Kw, 8192, 1024, 1024);
  gemm_bt<2><<<ggrid, 256, 0, stream>>>(xb, Wvb, Vt, 8192, 1024, 1024);

  attn_fwd<<<dim3(16, 64), 256, 0, stream>>>(Qw, Kw, Vt, Ow);

  gemm_bt<3><<<ggrid, 256, 0, stream>>>(Ow, Wob, out, 8192, 1024, 1024);
}

// Round 5
// 201.126 us; speedup vs baseline: 2.4104x; 1.2517x over previous
//
#include <hip/hip_runtime.h>
#include <hip/hip_bf16.h>

typedef __attribute__((ext_vector_type(8))) short short8;
typedef __attribute__((ext_vector_type(4))) float f32x4;
typedef __attribute__((ext_vector_type(16))) float f32x16;
typedef __attribute__((ext_vector_type(4))) unsigned short u16x4;

#define S_LEN 2048
#define DH 64
#define NH 16
#define SCALE_LOG2 0.18033688011112042f  // (1/8) * log2(e)
#define EXP2F(x) __builtin_amdgcn_exp2f(x)
#define GLOAD_LDS16(src, dst)                                             \
  __builtin_amdgcn_global_load_lds(                                       \
      (const __attribute__((address_space(1))) void*)(src),               \
      (__attribute__((address_space(3))) void*)(dst), 16, 0, 0)

__device__ __forceinline__ unsigned short f2bf(float f) {
  unsigned int u = __float_as_uint(f);
  u += 0x7fffu + ((u >> 16) & 1u);   // round-to-nearest-even
  return (unsigned short)(u >> 16);
}

__device__ __forceinline__ unsigned int cvtpk(float a, float b) {
  unsigned int r;
  asm("v_cvt_pk_bf16_f32 %0, %1, %2" : "=v"(r) : "v"(a), "v"(b));
  return r;
}
__device__ __forceinline__ void plswap(unsigned int& a, unsigned int& b) {
  asm("v_permlane32_swap_b32 %0, %1" : "+v"(a), "+v"(b));
}

__global__ void convert_f2bf(const float* __restrict__ in,
                             unsigned short* __restrict__ out, int n) {
  int i = (blockIdx.x * blockDim.x + threadIdx.x) * 4;
  if (i >= n) return;
  float4 v = *reinterpret_cast<const float4*>(in + i);
  u16x4 o;
  o.x = f2bf(v.x); o.y = f2bf(v.y); o.z = f2bf(v.z); o.w = f2bf(v.w);
  *reinterpret_cast<u16x4*>(out + i) = o;
}

// C = A @ B^T   (A: [M][K] bf16 row-major, B: [N][K] bf16 row-major)
// grid: (M/128, N/128) — m fastest so same-A-panel blocks share an XCD.
// MODE 0: out bf16 at [(b*16+h)*2048+s][64]  (K layout)
// MODE 1: like 0 but scaled by SCALE_LOG2    (Q layout)
// MODE 2: out bf16 at [(b*16+h)*64+d][2048]  (V transposed)
// MODE 3: out fp32 row-major [M][N]
template <int MODE>
__global__ __launch_bounds__(256) void gemm_bt(
    const unsigned short* __restrict__ A,
    const unsigned short* __restrict__ B,
    void* __restrict__ out, int M, int N, int K) {
  __shared__ __align__(16) unsigned short As[128 * 64];
  __shared__ __align__(16) unsigned short Bs[128 * 64];
  const int tid = threadIdx.x;
  const int l = tid & 63, w = tid >> 6;
  const int wr = w >> 1, wc = w & 1;
  const int g = l >> 4, c = l & 15;
  const int m0 = blockIdx.x * 128;
  const int n0 = blockIdx.y * 128;
  const int lrow = l >> 3, lcol = (l & 7) * 8;  // lane slot in 8-row pass

  f32x4 acc[4][4] = {};

  for (int k0 = 0; k0 < K; k0 += 64) {
#pragma unroll
    for (int p = 0; p < 4; ++p) {
      int r0 = w * 32 + p * 8;
      GLOAD_LDS16(&A[(long)(m0 + r0 + lrow) * K + k0 + lcol], &As[r0 * 64]);
      GLOAD_LDS16(&B[(long)(n0 + r0 + lrow) * K + k0 + lcol], &Bs[r0 * 64]);
    }
    __syncthreads();
#pragma unroll
    for (int s = 0; s < 2; ++s) {
      short8 af[4], bf[4];
#pragma unroll
      for (int m = 0; m < 4; ++m)
        af[m] = *reinterpret_cast<const short8*>(
            &As[(wr * 64 + m * 16 + c) * 64 + s * 32 + g * 8]);
#pragma unroll
      for (int n = 0; n < 4; ++n)
        bf[n] = *reinterpret_cast<const short8*>(
            &Bs[(wc * 64 + n * 16 + c) * 64 + s * 32 + g * 8]);
#pragma unroll
      for (int m = 0; m < 4; ++m)
#pragma unroll
        for (int n = 0; n < 4; ++n)
          acc[m][n] = __builtin_amdgcn_mfma_f32_16x16x32_bf16(
              af[m], bf[n], acc[m][n], 0, 0, 0);
    }
    __syncthreads();
  }

#pragma unroll
  for (int m = 0; m < 4; ++m) {
#pragma unroll
    for (int n = 0; n < 4; ++n) {
#pragma unroll
      for (int r = 0; r < 4; ++r) {
        int row = m0 + wr * 64 + m * 16 + g * 4 + r;
        int col = n0 + wc * 64 + n * 16 + c;
        float v = acc[m][n][r];
        if (MODE == 3) {
          reinterpret_cast<float*>(out)[(long)row * N + col] = v;
        } else if (MODE == 2) {
          int b = row >> 11, s = row & 2047;
          int h = col >> 6, d = col & 63;
          reinterpret_cast<unsigned short*>(
              out)[((long)((b * NH + h) * DH + d)) * S_LEN + s] = f2bf(v);
        } else {
          if (MODE == 1) v *= SCALE_LOG2;
          int b = row >> 11, s = row & 2047;
          int h = col >> 6, d = col & 63;
          reinterpret_cast<unsigned short*>(
              out)[((long)((b * NH + h) * S_LEN + s)) * DH + d] = f2bf(v);
        }
      }
    }
  }
}

// swizzled 8-elem-chunk offset within a row-major [R][64] bf16 tile
__device__ __forceinline__ int swz8c(int row, int chunk) {
  return row * 64 + ((chunk ^ (row & 7)) << 3);
}

// ---- attention v4: paired causal blocks, dbuf global_load_lds staging ----
// Q (pre-scaled by SCALE_LOG2), K: [bh][2048][64] bf16; Vt: [bh][64][2048];
// O: [b*2048+s][1024] bf16. Grid: (64 bh, 8 pp), 256 thr (4 waves).
// Block (bh,pp) processes q-blocks pp and 15-pp: uniform 34 tiles.
__global__ __launch_bounds__(256) void attn_fwd(
    const unsigned short* __restrict__ Q, const unsigned short* __restrict__ Kg,
    const unsigned short* __restrict__ Vt, unsigned short* __restrict__ O) {
  __shared__ __align__(16) unsigned short Ks[2][64 * 64];
  __shared__ __align__(16) unsigned short Vs[2][64 * 64];

  const int tid = threadIdx.x;
  const int l = tid & 63, w = tid >> 6;
  const int ln = l & 31, hi = l >> 5, hi4 = hi * 4;
  const int bh = blockIdx.x;
  const int pp = blockIdx.y;
  const int b = bh >> 4, h = bh & 15;
  const long base = (long)bh * (S_LEN * DH);
  const int sr8 = l >> 3;                 // 0..7: row within 8-row granule
  const int scol = ((l & 7) ^ sr8) * 8;   // pre-swizzled global source column

  for (int phase = 0; phase < 2; ++phase) {
    const int qb = phase ? (15 - pp) : pp;
    const int q0w = qb * 128 + w * 32;

    short8 qf[4];
    {
      const unsigned short* qp = Q + base + (long)(q0w + ln) * DH + hi * 8;
#pragma unroll
      for (int ks = 0; ks < 4; ++ks)
        qf[ks] = *reinterpret_cast<const short8*>(qp + ks * 16);
    }

    f32x16 o0 = {}, o1 = {};
    float m_r = -1e30f, l_r = 0.f;
    const int ntb = qb * 2 + 2;
    const int ntw = q0w / 64 + 1;

    // prologue: stage tile 0 into buf 0
#pragma unroll
    for (int p = 0; p < 2; ++p) {
      int r0 = w * 16 + p * 8;
      GLOAD_LDS16(&Kg[base + (long)(r0 + sr8) * DH + scol], &Ks[0][r0 * 64]);
      GLOAD_LDS16(&Vt[base + (long)(r0 + sr8) * S_LEN + scol], &Vs[0][r0 * 64]);
    }
    __syncthreads();

    int cur = 0;
    for (int t = 0; t < ntb; ++t) {
      if (t + 1 < ntb) {  // issue next-tile loads (hidden under compute)
        const int kv1 = (t + 1) * 64;
#pragma unroll
        for (int p = 0; p < 2; ++p) {
          int r0 = w * 16 + p * 8;
          GLOAD_LDS16(&Kg[base + (long)(kv1 + r0 + sr8) * DH + scol],
                      &Ks[cur ^ 1][r0 * 64]);
          GLOAD_LDS16(&Vt[base + (long)(r0 + sr8) * S_LEN + kv1 + scol],
                      &Vs[cur ^ 1][r0 * 64]);
        }
      }
      if (t < ntw) {
        const unsigned short* ksb = Ks[cur];
        const unsigned short* vsb = Vs[cur];
        const int kv0 = t * 64;

        f32x16 s0 = {}, s1 = {};
        __builtin_amdgcn_s_setprio(1);
#pragma unroll
        for (int ks = 0; ks < 4; ++ks) {
          short8 ak0 =
              *reinterpret_cast<const short8*>(&ksb[swz8c(ln, ks * 2 + hi)]);
          short8 ak1 = *reinterpret_cast<const short8*>(
              &ksb[swz8c(32 + ln, ks * 2 + hi)]);
          s0 = __builtin_amdgcn_mfma_f32_32x32x16_bf16(ak0, qf[ks], s0, 0, 0, 0);
          s1 = __builtin_amdgcn_mfma_f32_32x32x16_bf16(ak1, qf[ks], s1, 0, 0, 0);
        }
        __builtin_amdgcn_s_setprio(0);

        if (t == ntw - 1) {  // diagonal tile: causal mask (kv > q)
          const int qrel = (q0w - kv0) + ln;
#pragma unroll
          for (int r = 0; r < 16; ++r) {
            const int rowv = (r & 3) + 8 * (r >> 2) + hi4;
            if (rowv > qrel) s0[r] = -1e30f;
            if (rowv + 32 > qrel) s1[r] = -1e30f;
          }
        }

        float pm = -1e30f;
#pragma unroll
        for (int r = 0; r < 16; ++r) pm = fmaxf(pm, fmaxf(s0[r], s1[r]));
        pm = fmaxf(pm, __shfl_xor(pm, 32, 64));

        if (!__all(pm <= m_r + 8.0f)) {  // T13 defer-max
          float mn = fmaxf(m_r, pm);
          float sc = EXP2F(m_r - mn);
          m_r = mn;
          l_r *= sc;
#pragma unroll
          for (int r = 0; r < 16; ++r) {
            float sv = __shfl(sc, (r & 3) + 8 * (r >> 2) + hi4, 64);
            o0[r] *= sv;
            o1[r] *= sv;
          }
        }

        float ps = 0.f;
#pragma unroll
        for (int r = 0; r < 16; ++r) {
          s0[r] = EXP2F(s0[r] - m_r);
          s1[r] = EXP2F(s1[r] - m_r);
          ps += s0[r] + s1[r];
        }
        ps += __shfl_xor(ps, 32, 64);
        l_r += ps;

        // PV: rebuild P A-fragment in-register (T12) and accumulate O
        __builtin_amdgcn_s_setprio(1);
#pragma unroll
        for (int ks = 0; ks < 4; ++ks) {
          unsigned int wa, wb, wc2, wd;
          if (ks == 0) {
            wa = cvtpk(s0[0], s0[1]);  wc2 = cvtpk(s0[2], s0[3]);
            wb = cvtpk(s0[4], s0[5]);  wd  = cvtpk(s0[6], s0[7]);
          } else if (ks == 1) {
            wa = cvtpk(s0[8], s0[9]);  wc2 = cvtpk(s0[10], s0[11]);
            wb = cvtpk(s0[12], s0[13]); wd = cvtpk(s0[14], s0[15]);
          } else if (ks == 2) {
            wa = cvtpk(s1[0], s1[1]);  wc2 = cvtpk(s1[2], s1[3]);
            wb = cvtpk(s1[4], s1[5]);  wd  = cvtpk(s1[6], s1[7]);
          } else {
            wa = cvtpk(s1[8], s1[9]);  wc2 = cvtpk(s1[10], s1[11]);
            wb = cvtpk(s1[12], s1[13]); wd = cvtpk(s1[14], s1[15]);
          }
          plswap(wa, wb);   // -> word0, word2
          plswap(wc2, wd);  // -> word1, word3
          union { unsigned int u[4]; short8 s; } pa;
          pa.u[0] = wa; pa.u[1] = wc2; pa.u[2] = wb; pa.u[3] = wd;
          short8 v0 =
              *reinterpret_cast<const short8*>(&vsb[swz8c(ln, ks * 2 + hi)]);
          short8 v1 = *reinterpret_cast<const short8*>(
              &vsb[swz8c(32 + ln, ks * 2 + hi)]);
          o0 = __builtin_amdgcn_mfma_f32_32x32x16_bf16(pa.s, v0, o0, 0, 0, 0);
          o1 = __builtin_amdgcn_mfma_f32_32x32x16_bf16(pa.s, v1, o1, 0, 0, 0);
        }
        __builtin_amdgcn_s_setprio(0);
      }
      __syncthreads();
      cur ^= 1;
    }

    float inv = 1.0f / l_r;
#pragma unroll
    for (int r = 0; r < 16; ++r) {
      const int rowv = (r & 3) + 8 * (r >> 2) + hi4;
      float iv = __shfl(inv, rowv, 64);
      int q = q0w + rowv;
      long ob = ((long)(b * S_LEN + q)) * 1024 + h * 64 + ln;
      O[ob] = f2bf(o0[r] * iv);
      O[ob + 32] = f2bf(o1[r] * iv);
    }
  }
}

extern "C" void kernel_launch(void* const* d_in, const int* in_sizes, int n_in,
                              void* d_out, int out_size, void* d_ws,
                              size_t ws_size, hipStream_t stream) {
  const float* x  = (const float*)d_in[0];
  const float* Wq = (const float*)d_in[1];
  const float* Wk = (const float*)d_in[2];
  const float* Wv = (const float*)d_in[3];
  const float* Wo = (const float*)d_in[4];
  float* out = (float*)d_out;
  char* ws = (char*)d_ws;

  unsigned short* xb  = (unsigned short*)(ws);                   // 16 MB
  unsigned short* Wqb = (unsigned short*)(ws + (16u << 20));
  unsigned short* Wkb = (unsigned short*)(ws + (18u << 20));
  unsigned short* Wvb = (unsigned short*)(ws + (20u << 20));
  unsigned short* Wob = (unsigned short*)(ws + (22u << 20));
  unsigned short* Vt  = (unsigned short*)(ws + (24u << 20));     // 16 MB
  unsigned short* Ow  = (unsigned short*)(ws);                   // alias xb
  unsigned short* Qw = (unsigned short*)d_out;                   // scratch in d_out
  unsigned short* Kw = (unsigned short*)d_out + (8u << 20);

  const int NX = 8 * 1024 * 1024, NW = 1024 * 1024;
  convert_f2bf<<<NX / 1024, 256, 0, stream>>>(x, xb, NX);
  convert_f2bf<<<NW / 1024, 256, 0, stream>>>(Wq, Wqb, NW);
  convert_f2bf<<<NW / 1024, 256, 0, stream>>>(Wk, Wkb, NW);
  convert_f2bf<<<NW / 1024, 256, 0, stream>>>(Wv, Wvb, NW);
  convert_f2bf<<<NW / 1024, 256, 0, stream>>>(Wo, Wob, NW);

  dim3 ggrid(64, 8);  // (M/128, N/128) — m fastest: A-panel sharers on one XCD
  gemm_bt<1><<<ggrid, 256, 0, stream>>>(xb, Wqb, Qw, 8192, 1024, 1024);
  gemm_bt<0><<<ggrid, 256, 0, stream>>>(xb, Wkb, Kw, 8192, 1024, 1024);
  gemm_bt<2><<<ggrid, 256, 0, stream>>>(xb, Wvb, Vt, 8192, 1024, 1024);

  attn_fwd<<<dim3(64, 8), 256, 0, stream>>>(Qw, Kw, Vt, Ow);

  gemm_bt<3><<<ggrid, 256, 0, stream>>>(Ow, Wob, out, 8192, 1024, 1024);
}